// Round 8
// baseline (267.142 us; speedup 1.0000x reference)
//
#include <hip/hip_runtime.h>
#include <hip/hip_cooperative_groups.h>
#include <stdint.h>
#include <math.h>

namespace cg = cooperative_groups;

#define NLVL  16
#define NPTS  131072
#define BPTS  64
#define NTHR  256
#define NBINS 8192              // key = z(2) | y(4) | x(7)
#define NWIN  (NPTS / BPTS)     // 2048 windows
#define GRID  768               // 3 blocks/CU guaranteed residency (LDS-capped 4)

// ws layout
#define OFF_HIST 0
#define OFF_PID  (NBINS * 4)                    // 32 KB
#define OFF_XYZS (OFF_PID + NPTS * 4)           // +512 KB
#define WS_NEED  (OFF_XYZS + NPTS * 12)         // +1.5 MB  ~= 2.03 MB

struct Meta {
  int scales[NLVL];
  int offsets[NLVL];
  unsigned int T;
  int start_hash;
  double invT;
};

// h < 2^38, T ~ 2^19. (double)h exact; q off by at most +-1, fixed up.
__device__ __forceinline__ int fastmod(uint64_t h, unsigned int T, double invT) {
  uint64_t q = (uint64_t)((double)h * invT);
  long long r = (long long)(h - q * (uint64_t)T);
  if (r < 0) r += (long long)T;
  else if (r >= (long long)T) r -= (long long)T;
  return (int)r;
}

// 8 corner indices (level offset folded in) + fractional offsets for level l.
// Bit-matches fp32 reference: corner index = (int)(fx + corner_f32).
__device__ __forceinline__ void level_idx(
    int l, float xn, float yn, float zn, const Meta& m,
    int* __restrict__ idx, float* __restrict__ o)
{
#pragma clang fp contract(off)
  const float sf = (float)m.scales[l];
  const float fx = xn * sf, fy = yn * sf, fz = zn * sf;
  const int ix0 = (int)fx,          iy0 = (int)fy,          iz0 = (int)fz;
  const int ix1 = (int)(fx + 1.0f), iy1 = (int)(fy + 1.0f), iz1 = (int)(fz + 1.0f);
  o[0] = fx - (float)ix0; o[1] = fy - (float)iy0; o[2] = fz - (float)iz0;
  const int base = m.offsets[l];

  if (l < m.start_hash) {
    const int sp1 = m.scales[l] + 1;
    const int sq  = sp1 * sp1;
    const int ax0 = ix0 * sq,  ax1 = ix1 * sq;
    const int ay0 = iy0 * sp1, ay1 = iy1 * sp1;
    idx[0] = base + ax0 + ay0 + iz0;
    idx[1] = base + ax0 + ay0 + iz1;
    idx[2] = base + ax0 + ay1 + iz0;
    idx[3] = base + ax0 + ay1 + iz1;
    idx[4] = base + ax1 + ay0 + iz0;
    idx[5] = base + ax1 + ay0 + iz1;
    idx[6] = base + ax1 + ay1 + iz0;
    idx[7] = base + ax1 + ay1 + iz1;
  } else {
    const uint64_t hx0 = (uint64_t)ix0;
    const uint64_t hx1 = (uint64_t)ix1;
    const uint64_t hy0 = (uint64_t)iy0 * 19349663ull;
    const uint64_t hy1 = hy0 + 19349663ull;
    const uint64_t hz0 = (uint64_t)iz0 * 83492791ull;
    const uint64_t hz1 = hz0 + 83492791ull;
    idx[0] = base + fastmod(hx0 ^ hy0 ^ hz0, m.T, m.invT);
    idx[1] = base + fastmod(hx0 ^ hy0 ^ hz1, m.T, m.invT);
    idx[2] = base + fastmod(hx0 ^ hy1 ^ hz0, m.T, m.invT);
    idx[3] = base + fastmod(hx0 ^ hy1 ^ hz1, m.T, m.invT);
    idx[4] = base + fastmod(hx1 ^ hy0 ^ hz0, m.T, m.invT);
    idx[5] = base + fastmod(hx1 ^ hy0 ^ hz1, m.T, m.invT);
    idx[6] = base + fastmod(hx1 ^ hy1 ^ hz0, m.T, m.invT);
    idx[7] = base + fastmod(hx1 ^ hy1 ^ hz1, m.T, m.invT);
  }
}

__device__ __forceinline__ int coarse_key(float xn, float yn, float zn) {
  const int kx = min((int)(xn * 128.0f), 127);
  const int ky = min((int)(yn * 16.0f), 15);
  const int kz = min((int)(zn * 4.0f), 3);
  return ((kz * 16 + ky) * 128) + kx;     // lexicographic (z,y,x), x fastest
}

// Single cooperative kernel: global counting sort by coarse spatial key,
// then R4-style compute over spatially-coherent 64-point windows.
__global__ __launch_bounds__(NTHR) void hg_coop(
    const float* __restrict__ xyz,
    const float* __restrict__ wb,
    const float* __restrict__ data,
    float* __restrict__ out,
    int* __restrict__ hist,       // ws: NBINS (pre-zeroed by memset)
    int* __restrict__ pid_s,      // ws: NPTS
    float* __restrict__ xyz_s,    // ws: NPTS*3
    Meta meta)
{
#pragma clang fp contract(off)
  cg::grid_group grid = cg::this_grid();
  const int t   = threadIdx.x;
  const int bid = blockIdx.x;

  __shared__ union {
    int lhist[NBINS];                          // phases A,B,C (32 KB)
    struct {
      float  sxyz[BPTS * 3];
      int    h[64];
      int    sidx[BPTS];
      int    spid[BPTS];
      float2 tile[BPTS][NLVL + 1];
    } d;                                       // phase D (~10.2 KB)
  } sm;
  __shared__ int part[NTHR];

  const float bx0 = wb[0], by0 = wb[1], bz0 = wb[2];
  const float bx1 = wb[3], by1 = wb[4], bz1 = wb[5];
  const float denom = fmaxf(fmaxf(bx1 - bx0, by1 - by0), bz1 - bz0) + 1e-6f;

  // ---------------- Phase A: histogram (blocks 0..511, 256 pts each) -------
  if (bid < NPTS / NTHR) {
    for (int i = t; i < NBINS; i += NTHR) sm.lhist[i] = 0;
    __syncthreads();
    const int p = bid * NTHR + t;
    const float x = xyz[3 * p + 0], y = xyz[3 * p + 1], z = xyz[3 * p + 2];
    const float xn = (fminf(fmaxf(x, bx0), bx1) - bx0) / denom;
    const float yn = (fminf(fmaxf(y, by0), by1) - by0) / denom;
    const float zn = (fminf(fmaxf(z, bz0), bz1) - bz0) / denom;
    atomicAdd(&sm.lhist[coarse_key(xn, yn, zn)], 1);
    __syncthreads();
    for (int i = t; i < NBINS; i += NTHR) {
      const int c = sm.lhist[i];
      if (c) atomicAdd(&hist[i], c);
    }
  }
  grid.sync();

  // ---------------- Phase B: exclusive scan of hist (block 0) --------------
  if (bid == 0) {
    for (int i = t; i < NBINS; i += NTHR) sm.lhist[i] = hist[i];
    __syncthreads();
    const int base = t * (NBINS / NTHR);       // 32 per thread
    int s = 0;
#pragma unroll
    for (int j = 0; j < NBINS / NTHR; ++j) {
      const int v = sm.lhist[base + j];
      sm.lhist[base + j] = s;
      s += v;
    }
    part[t] = s;
    __syncthreads();
    if (t == 0) {
      int run = 0;
      for (int i = 0; i < NTHR; ++i) { const int v = part[i]; part[i] = run; run += v; }
    }
    __syncthreads();
    const int add = part[t];
#pragma unroll
    for (int j = 0; j < NBINS / NTHR; ++j)
      hist[base + j] = sm.lhist[base + j] + add;
  }
  grid.sync();

  // ---------------- Phase C: rank + scatter (blocks 0..511) ----------------
  if (bid < NPTS / NTHR) {
    for (int i = t; i < NBINS; i += NTHR) sm.lhist[i] = 0;
    __syncthreads();
    const int p = bid * NTHR + t;
    const float x = xyz[3 * p + 0], y = xyz[3 * p + 1], z = xyz[3 * p + 2];
    const float xn = (fminf(fmaxf(x, bx0), bx1) - bx0) / denom;
    const float yn = (fminf(fmaxf(y, by0), by1) - by0) / denom;
    const float zn = (fminf(fmaxf(z, bz0), bz1) - bz0) / denom;
    const int key = coarse_key(xn, yn, zn);
    const int myrank = atomicAdd(&sm.lhist[key], 1);
    __syncthreads();
    // convert block counts -> global bases (cursor advance, one atomic/bin)
    for (int i = t; i < NBINS; i += NTHR) {
      const int c = sm.lhist[i];
      if (c) sm.lhist[i] = atomicAdd(&hist[i], c);
    }
    __syncthreads();
    const int pos = sm.lhist[key] + myrank;
    pid_s[pos] = p;
    xyz_s[pos * 3 + 0] = x;
    xyz_s[pos * 3 + 1] = y;
    xyz_s[pos * 3 + 2] = z;
  }
  grid.sync();

  // ---------------- Phase D: compute over sorted 64-pt windows -------------
  const int wave = t >> 6;
  const int lane = t & 63;
  const float2* __restrict__ dp = (const float2*)data;
  const float sf15 = (float)meta.scales[NLVL - 1];

  for (int w = bid; w < NWIN; w += gridDim.x) {
    __syncthreads();                            // LDS reuse guard
    for (int i = t; i < BPTS * 3; i += NTHR) sm.d.sxyz[i] = xyz_s[w * BPTS * 3 + i];
    if (t < 64) {
      sm.d.spid[t] = pid_s[w * BPTS + t];
      sm.d.h[t] = 0;
    }
    __syncthreads();

    // local fine sort by level-15 cell (window is spatially coherent)
    int key = 0;
    if (t < 64) {
      const float px = fminf(fmaxf(sm.d.sxyz[t * 3 + 0], bx0), bx1);
      const float py = fminf(fmaxf(sm.d.sxyz[t * 3 + 1], by0), by1);
      const float pz = fminf(fmaxf(sm.d.sxyz[t * 3 + 2], bz0), bz1);
      const int kx = (int)(((px - bx0) / denom) * sf15);
      const int ky = (int)(((py - by0) / denom) * sf15);
      const int kz = (int)(((pz - bz0) / denom) * sf15);
      key = (kx + ky * 7 + kz * 29) & 63;
      atomicAdd(&sm.d.h[key], 1);
    }
    __syncthreads();
    if (t < 64) {
      int v = sm.d.h[t];
#pragma unroll
      for (int d = 1; d < 64; d <<= 1) {
        const int u = __shfl_up(v, d, 64);
        if (lane >= d) v += u;
      }
      sm.d.h[t] = v;
    }
    __syncthreads();
    if (t < 64) {
      const int pos = atomicSub(&sm.d.h[key], 1) - 1;
      sm.d.sidx[pos] = t;
    }
    __syncthreads();

    const int slot = sm.d.sidx[lane];
    const float px = fminf(fmaxf(sm.d.sxyz[slot * 3 + 0], bx0), bx1);
    const float py = fminf(fmaxf(sm.d.sxyz[slot * 3 + 1], by0), by1);
    const float pz = fminf(fmaxf(sm.d.sxyz[slot * 3 + 2], bz0), bz1);
    const float xn = (px - bx0) / denom;
    const float yn = (py - by0) / denom;
    const float zn = (pz - bz0) / denom;

#pragma unroll 2
    for (int s = 0; s < 4; ++s) {
      const int l = wave + 4 * s;
      int idx[8];
      float o[3];
      level_idx(l, xn, yn, zn, meta, idx, o);
      float2 v[8];
#pragma unroll
      for (int k = 0; k < 8; ++k) v[k] = dp[idx[k]];
      const float wx[2] = {1.0f - o[0], o[0]};
      const float wy[2] = {1.0f - o[1], o[1]};
      const float wz[2] = {1.0f - o[2], o[2]};
      float a0 = 0.0f, a1 = 0.0f;
#pragma unroll
      for (int c = 0; c < 8; ++c) {
        const float ww = (wx[(c >> 2) & 1] * wy[(c >> 1) & 1]) * wz[c & 1];
        a0 += ww * v[c].x;
        a1 += ww * v[c].y;
      }
      sm.d.tile[slot][l] = make_float2(a0, a1);
    }
    __syncthreads();

    // 128 B-aligned per-point chunks; 8 adjacent threads per point.
#pragma unroll
    for (int it = 0; it < 2; ++it) {
      const int idx2 = t + it * NTHR;
      const int pp = idx2 >> 3;
      const int q  = idx2 & 7;
      const int pid = sm.d.spid[pp];
      const float2 e0 = sm.d.tile[pp][2 * q];
      const float2 e1 = sm.d.tile[pp][2 * q + 1];
      reinterpret_cast<float4*>(out)[pid * 8 + q] =
          make_float4(e0.x, e0.y, e1.x, e1.y);
    }
  }
}

// ---------------- Fallback: R4 single kernel (if ws too small) --------------
__global__ __launch_bounds__(NTHR) void hashgrid_fwd(
    const float* __restrict__ xyz,
    const float* __restrict__ wb,
    const float* __restrict__ data,
    float* __restrict__ out,
    Meta meta)
{
#pragma clang fp contract(off)
  const int t    = threadIdx.x;
  const int wave = t >> 6;
  const int lane = t & 63;
  const int pbase = blockIdx.x * BPTS;

  __shared__ float  sxyz[BPTS * 3];
  __shared__ int    hist[64];
  __shared__ int    sidx[BPTS];
  __shared__ float2 tile[BPTS][NLVL + 1];

  if (t < 48)
    reinterpret_cast<float4*>(sxyz)[t] =
        reinterpret_cast<const float4*>(xyz + pbase * 3)[t];
  if (t < 64) hist[t] = 0;
  __syncthreads();

  const float bx0 = wb[0], by0 = wb[1], bz0 = wb[2];
  const float bx1 = wb[3], by1 = wb[4], bz1 = wb[5];
  const float denom = fmaxf(fmaxf(bx1 - bx0, by1 - by0), bz1 - bz0) + 1e-6f;

  int key = 0;
  if (t < 64) {
    float px = fminf(fmaxf(sxyz[t * 3 + 0], bx0), bx1);
    float py = fminf(fmaxf(sxyz[t * 3 + 1], by0), by1);
    float pz = fminf(fmaxf(sxyz[t * 3 + 2], bz0), bz1);
    const float xn = (px - bx0) / denom;
    const float yn = (py - by0) / denom;
    const float zn = (pz - bz0) / denom;
    const int kx = min((int)(xn * 4.0f), 3);
    const int ky = min((int)(yn * 4.0f), 3);
    const int kz = min((int)(zn * 4.0f), 3);
    key = kx * 16 + ky * 4 + kz;
    atomicAdd(&hist[key], 1);
  }
  __syncthreads();
  if (t < 64) {
    int v = hist[t];
#pragma unroll
    for (int d = 1; d < 64; d <<= 1) {
      int u = __shfl_up(v, d, 64);
      if (lane >= d) v += u;
    }
    hist[t] = v;
  }
  __syncthreads();
  if (t < 64) {
    const int pos = atomicSub(&hist[key], 1) - 1;
    sidx[pos] = t;
  }
  __syncthreads();

  const int p = sidx[lane];
  float px = fminf(fmaxf(sxyz[p * 3 + 0], bx0), bx1);
  float py = fminf(fmaxf(sxyz[p * 3 + 1], by0), by1);
  float pz = fminf(fmaxf(sxyz[p * 3 + 2], bz0), bz1);
  const float xn = (px - bx0) / denom;
  const float yn = (py - by0) / denom;
  const float zn = (pz - bz0) / denom;

  const float2* __restrict__ dp = (const float2*)data;

#pragma unroll 2
  for (int s = 0; s < 4; ++s) {
    const int l = wave + 4 * s;
    int idx[8];
    float o[3];
    level_idx(l, xn, yn, zn, meta, idx, o);
    float2 v[8];
#pragma unroll
    for (int k = 0; k < 8; ++k) v[k] = dp[idx[k]];
    const float wx[2] = {1.0f - o[0], o[0]};
    const float wy[2] = {1.0f - o[1], o[1]};
    const float wz[2] = {1.0f - o[2], o[2]};
    float a0 = 0.0f, a1 = 0.0f;
#pragma unroll
    for (int c = 0; c < 8; ++c) {
      const float w = (wx[(c >> 2) & 1] * wy[(c >> 1) & 1]) * wz[c & 1];
      a0 += w * v[c].x;
      a1 += w * v[c].y;
    }
    tile[p][l] = make_float2(a0, a1);
  }
  __syncthreads();

#pragma unroll
  for (int it = 0; it < 2; ++it) {
    const int idx2 = t + it * NTHR;
    const int pp = idx2 >> 3;
    const int q  = idx2 & 7;
    const float2 e0 = tile[pp][2 * q];
    const float2 e1 = tile[pp][2 * q + 1];
    reinterpret_cast<float4*>(out)[(pbase + pp) * 8 + q] =
        make_float4(e0.x, e0.y, e1.x, e1.y);
  }
}

static bool isprime_ll(long long v) {
  if (v < 2) return false;
  for (long long i = 2; i * i <= v; ++i)
    if (v % i == 0) return false;
  return true;
}

extern "C" void kernel_launch(void* const* d_in, const int* in_sizes, int n_in,
                              void* d_out, int out_size, void* d_ws, size_t ws_size,
                              hipStream_t stream) {
  (void)in_sizes; (void)n_in; (void)out_size;

  Meta m;
  long long T = 1LL << 19;
  while (!isprime_ll(T)) ++T;
  const double b = pow(2048.0 / 16.0, 1.0 / 15.0);
  long long off = 0;
  int sh = -1;
  for (int i = 0; i < NLVL; ++i) {
    const int res = (int)(16.0 * pow(b, (double)i));   // matches int(16 * b**i)
    m.scales[i] = res;
    m.offsets[i] = (int)off;
    long long nn = (long long)(res + 1) * (res + 1) * (res + 1);
    if (nn > T) { if (sh < 0) sh = i; nn = T; }
    off += nn;
  }
  m.T = (unsigned int)T;
  m.start_hash = (sh < 0) ? NLVL : sh;
  m.invT = 1.0 / (double)T;

  const float* xyz  = (const float*)d_in[0];
  const float* wbp  = (const float*)d_in[1];
  const float* data = (const float*)d_in[2];
  float* out = (float*)d_out;

  if (ws_size < (size_t)WS_NEED) {
    hipLaunchKernelGGL(hashgrid_fwd, dim3(NPTS / BPTS), dim3(NTHR), 0, stream,
                       xyz, wbp, data, out, m);
    return;
  }

  char* ws = (char*)d_ws;
  int*   hist  = (int*)(ws + OFF_HIST);
  int*   pids  = (int*)(ws + OFF_PID);
  float* xyzs  = (float*)(ws + OFF_XYZS);

  hipMemsetAsync(hist, 0, NBINS * sizeof(int), stream);

  void* args[] = {(void*)&xyz, (void*)&wbp, (void*)&data, (void*)&out,
                  (void*)&hist, (void*)&pids, (void*)&xyzs, (void*)&m};
  hipLaunchCooperativeKernel((const void*)hg_coop, dim3(GRID), dim3(NTHR),
                             args, 0, stream);
}

// Round 9
// 36.262 us; speedup vs baseline: 7.3671x; 7.3671x over previous
//
#include <hip/hip_runtime.h>
#include <stdint.h>
#include <math.h>

#define NLVL 16
#define NPTS 131072
#define BPTS 64            // points per block
#define NTHR 256           // 4 waves

struct Meta {
  int scales[NLVL];
  int offsets[NLVL];      // element offsets (max ~6.1M, fits int32)
  unsigned int T;
  int start_hash;
  double invT;
};

// h < 2^38, T ~ 2^19. (double)h exact; q off by at most +-1, fixed up.
__device__ __forceinline__ int fastmod(uint64_t h, unsigned int T, double invT) {
  uint64_t q = (uint64_t)((double)h * invT);
  long long r = (long long)(h - q * (uint64_t)T);
  if (r < 0) r += (long long)T;
  else if (r >= (long long)T) r -= (long long)T;
  return (int)r;
}

// Block = 256 threads = 4 waves; block owns 64 points.
// Wave w computes levels {w, w+4, w+8, w+12}.
// Points are block-locally counting-sorted by a spatial key (x-fine, since
// ~82% of points have y,z clipped to the box min) so duplicate / nearby
// points sit in adjacent lanes -> the HW coalescer merges their lines.
// Dense levels (l < start_hash): (z0,z1) corner pairs are adjacent float2
// table entries -> merged into one float4 load (8 -> 4 gather instructions),
// with a rare patch branch for the iz1 != iz0+1 float-rounding case.
__global__ __launch_bounds__(NTHR) void hashgrid_fwd(
    const float* __restrict__ xyz,
    const float* __restrict__ wb,
    const float* __restrict__ data,
    float* __restrict__ out,
    Meta meta)
{
#pragma clang fp contract(off)
  const int t    = threadIdx.x;
  const int wave = t >> 6;
  const int lane = t & 63;
  const int pbase = blockIdx.x * BPTS;

  __shared__ float  sxyz[BPTS * 3];      // 768 B
  __shared__ int    hist[64];            // spatial-key histogram
  __shared__ int    sidx[BPTS];          // sorted -> original point slot
  __shared__ float2 tile[BPTS][NLVL + 1];// +1 pad to spread banks

  if (t < 48)
    reinterpret_cast<float4*>(sxyz)[t] =
        reinterpret_cast<const float4*>(xyz + pbase * 3)[t];
  if (t < 64) hist[t] = 0;
  __syncthreads();

  const float bx0 = wb[0], by0 = wb[1], bz0 = wb[2];
  const float bx1 = wb[3], by1 = wb[4], bz1 = wb[5];
  const float denom = fmaxf(fmaxf(bx1 - bx0, by1 - by0), bz1 - bz0) + 1e-6f;

  // ---- Phase 1: key per original point, histogram ----
  int key = 0;
  if (t < 64) {
    float px = fminf(fmaxf(sxyz[t * 3 + 0], bx0), bx1);
    float py = fminf(fmaxf(sxyz[t * 3 + 1], by0), by1);
    float pz = fminf(fmaxf(sxyz[t * 3 + 2], bz0), bz1);
    const float xn = (px - bx0) / denom;
    const float yn = (py - by0) / denom;
    const float zn = (pz - bz0) / denom;
    const int kx = min((int)(xn * 16.0f), 15);
    const int ky = min((int)(yn * 2.0f), 1);
    const int kz = min((int)(zn * 2.0f), 1);
    key = (((kz << 1) | ky) << 4) | kx;
    atomicAdd(&hist[key], 1);
  }
  __syncthreads();

  // ---- Phase 2: inclusive scan of 64 bins (wave 0 shuffle scan) ----
  if (t < 64) {
    int v = hist[t];
#pragma unroll
    for (int d = 1; d < 64; d <<= 1) {
      int u = __shfl_up(v, d, 64);
      if (lane >= d) v += u;
    }
    hist[t] = v;   // inclusive prefix (bin end offset)
  }
  __syncthreads();

  // ---- Phase 3: scatter into sorted order (fill each bin from its end) ----
  if (t < 64) {
    const int pos = atomicSub(&hist[key], 1) - 1;
    sidx[pos] = t;
  }
  __syncthreads();

  // ---- Phase 4: compute; lane processes sorted point ----
  const int p = sidx[lane];
  float px = fminf(fmaxf(sxyz[p * 3 + 0], bx0), bx1);
  float py = fminf(fmaxf(sxyz[p * 3 + 1], by0), by1);
  float pz = fminf(fmaxf(sxyz[p * 3 + 2], bz0), bz1);
  const float xn = (px - bx0) / denom;
  const float yn = (py - by0) / denom;
  const float zn = (pz - bz0) / denom;

  const float2* __restrict__ dp = (const float2*)data;

#pragma unroll 2
  for (int s = 0; s < 4; ++s) {
    const int l = wave + 4 * s;

    const float sf = (float)meta.scales[l];
    const float fx = xn * sf, fy = yn * sf, fz = zn * sf;
    const int ix0 = (int)fx,          iy0 = (int)fy,          iz0 = (int)fz;
    const int ix1 = (int)(fx + 1.0f), iy1 = (int)(fy + 1.0f), iz1 = (int)(fz + 1.0f);
    const float o0 = fx - (float)ix0, o1 = fy - (float)iy0, o2 = fz - (float)iz0;
    const int base = meta.offsets[l];

    float2 v[8];
    if (l < meta.start_hash) {
      // Dense: z-pairs are adjacent elements -> one float4 per (x,y) pair.
      const int sp1 = meta.scales[l] + 1;
      const int sq  = sp1 * sp1;
      const int ax0 = ix0 * sq,  ax1 = ix1 * sq;
      const int ay0 = iy0 * sp1, ay1 = iy1 * sp1;
      const int i00 = base + ax0 + ay0 + iz0;
      const int i01 = base + ax0 + ay1 + iz0;
      const int i10 = base + ax1 + ay0 + iz0;
      const int i11 = base + ax1 + ay1 + iz0;
      const float4 q00 = *reinterpret_cast<const float4*>(dp + i00);
      const float4 q01 = *reinterpret_cast<const float4*>(dp + i01);
      const float4 q10 = *reinterpret_cast<const float4*>(dp + i10);
      const float4 q11 = *reinterpret_cast<const float4*>(dp + i11);
      v[0] = make_float2(q00.x, q00.y); v[1] = make_float2(q00.z, q00.w);
      v[2] = make_float2(q01.x, q01.y); v[3] = make_float2(q01.z, q01.w);
      v[4] = make_float2(q10.x, q10.y); v[5] = make_float2(q10.z, q10.w);
      v[6] = make_float2(q11.x, q11.y); v[7] = make_float2(q11.z, q11.w);
      // Rare: (int)(fz+1.0f) may round to iz0+2 when fz is ~1 ulp below an
      // integer. Patch the z1 corners with the true index. execz-skipped
      // almost always.
      if (__builtin_expect(iz1 != iz0 + 1, 0)) {
        v[1] = dp[base + ax0 + ay0 + iz1];
        v[3] = dp[base + ax0 + ay1 + iz1];
        v[5] = dp[base + ax1 + ay0 + iz1];
        v[7] = dp[base + ax1 + ay1 + iz1];
      }
    } else {
      const uint64_t hx0 = (uint64_t)ix0;
      const uint64_t hx1 = (uint64_t)ix1;
      const uint64_t hy0 = (uint64_t)iy0 * 19349663ull;
      const uint64_t hy1 = hy0 + 19349663ull;      // iy1 == iy0+1 for hashed l
      const uint64_t hz0 = (uint64_t)iz0 * 83492791ull;
      const uint64_t hz1 = hz0 + 83492791ull;
      v[0] = dp[base + fastmod(hx0 ^ hy0 ^ hz0, meta.T, meta.invT)];
      v[1] = dp[base + fastmod(hx0 ^ hy0 ^ hz1, meta.T, meta.invT)];
      v[2] = dp[base + fastmod(hx0 ^ hy1 ^ hz0, meta.T, meta.invT)];
      v[3] = dp[base + fastmod(hx0 ^ hy1 ^ hz1, meta.T, meta.invT)];
      v[4] = dp[base + fastmod(hx1 ^ hy0 ^ hz0, meta.T, meta.invT)];
      v[5] = dp[base + fastmod(hx1 ^ hy0 ^ hz1, meta.T, meta.invT)];
      v[6] = dp[base + fastmod(hx1 ^ hy1 ^ hz0, meta.T, meta.invT)];
      v[7] = dp[base + fastmod(hx1 ^ hy1 ^ hz1, meta.T, meta.invT)];
    }

    const float wx[2] = {1.0f - o0, o0};
    const float wy[2] = {1.0f - o1, o1};
    const float wz[2] = {1.0f - o2, o2};
    float a0 = 0.0f, a1 = 0.0f;
#pragma unroll
    for (int c = 0; c < 8; ++c) {
      const float w = (wx[(c >> 2) & 1] * wy[(c >> 1) & 1]) * wz[c & 1];
      a0 += w * v[c].x;
      a1 += w * v[c].y;
    }
    tile[p][l] = make_float2(a0, a1);
  }
  __syncthreads();

  // ---- Phase 5: coalesced float4 store in original order ----
#pragma unroll
  for (int it = 0; it < 2; ++it) {
    const int idx2 = t + it * NTHR;      // 0..511 float4s
    const int pp = idx2 >> 3;            // point
    const int q  = idx2 & 7;             // float4 within point (levels 2q,2q+1)
    const float2 e0 = tile[pp][2 * q];
    const float2 e1 = tile[pp][2 * q + 1];
    reinterpret_cast<float4*>(out)[(pbase + pp) * 8 + q] =
        make_float4(e0.x, e0.y, e1.x, e1.y);
  }
}

static bool isprime_ll(long long v) {
  if (v < 2) return false;
  for (long long i = 2; i * i <= v; ++i)
    if (v % i == 0) return false;
  return true;
}

extern "C" void kernel_launch(void* const* d_in, const int* in_sizes, int n_in,
                              void* d_out, int out_size, void* d_ws, size_t ws_size,
                              hipStream_t stream) {
  (void)in_sizes; (void)n_in; (void)d_ws; (void)ws_size; (void)out_size;

  Meta m;
  long long T = 1LL << 19;
  while (!isprime_ll(T)) ++T;
  const double b = pow(2048.0 / 16.0, 1.0 / 15.0);
  long long off = 0;
  int sh = -1;
  for (int i = 0; i < NLVL; ++i) {
    const int res = (int)(16.0 * pow(b, (double)i));   // matches int(16 * b**i)
    m.scales[i] = res;
    m.offsets[i] = (int)off;
    long long nn = (long long)(res + 1) * (res + 1) * (res + 1);
    if (nn > T) { if (sh < 0) sh = i; nn = T; }
    off += nn;
  }
  m.T = (unsigned int)T;
  m.start_hash = (sh < 0) ? NLVL : sh;
  m.invT = 1.0 / (double)T;

  const float* xyz  = (const float*)d_in[0];
  const float* wbp  = (const float*)d_in[1];
  const float* data = (const float*)d_in[2];
  float* out = (float*)d_out;

  hipLaunchKernelGGL(hashgrid_fwd, dim3(NPTS / BPTS), dim3(NTHR), 0, stream,
                     xyz, wbp, data, out, m);
}

// Round 11
// 32.386 us; speedup vs baseline: 8.2488x; 1.1197x over previous
//
#include <hip/hip_runtime.h>
#include <stdint.h>
#include <math.h>

#define NLVL 16
#define NPTS 131072
#define BPTS 64            // points per block
#define NTHR 256           // 4 waves

typedef float floatx4 __attribute__((ext_vector_type(4)));

struct Meta {
  int scales[NLVL];
  int offsets[NLVL];      // element offsets (max ~6.1M, fits int32)
  unsigned int T;
  int start_hash;
  double invT;
};

// h < 2^38, T ~ 2^19. (double)h is exact; q off by at most +-1, fixed up.
__device__ __forceinline__ int fastmod(uint64_t h, unsigned int T, double invT) {
  uint64_t q = (uint64_t)((double)h * invT);
  long long r = (long long)(h - q * (uint64_t)T);
  if (r < 0) r += (long long)T;
  else if (r >= (long long)T) r -= (long long)T;
  return (int)r;
}

// 8 corner indices (level offset folded in) + fractional offsets for level l.
// Bit-matches fp32 reference: corner index = (int)(fx + corner_f32).
__device__ __forceinline__ void level_idx(
    int l, float xn, float yn, float zn, const Meta& m,
    int* __restrict__ idx, float* __restrict__ o)
{
#pragma clang fp contract(off)
  const float sf = (float)m.scales[l];
  const float fx = xn * sf, fy = yn * sf, fz = zn * sf;
  const int ix0 = (int)fx,          iy0 = (int)fy,          iz0 = (int)fz;
  const int ix1 = (int)(fx + 1.0f), iy1 = (int)(fy + 1.0f), iz1 = (int)(fz + 1.0f);
  o[0] = fx - (float)ix0; o[1] = fy - (float)iy0; o[2] = fz - (float)iz0;
  const int base = m.offsets[l];

  if (l < m.start_hash) {
    const int sp1 = m.scales[l] + 1;
    const int sq  = sp1 * sp1;
    const int ax0 = ix0 * sq,  ax1 = ix1 * sq;
    const int ay0 = iy0 * sp1, ay1 = iy1 * sp1;
    idx[0] = base + ax0 + ay0 + iz0;
    idx[1] = base + ax0 + ay0 + iz1;
    idx[2] = base + ax0 + ay1 + iz0;
    idx[3] = base + ax0 + ay1 + iz1;
    idx[4] = base + ax1 + ay0 + iz0;
    idx[5] = base + ax1 + ay0 + iz1;
    idx[6] = base + ax1 + ay1 + iz0;
    idx[7] = base + ax1 + ay1 + iz1;
  } else {
    const uint64_t hx0 = (uint64_t)ix0;
    const uint64_t hx1 = (uint64_t)ix1;          // = hx0 + 1
    const uint64_t hy0 = (uint64_t)iy0 * 19349663ull;
    const uint64_t hy1 = hy0 + 19349663ull;      // iy1 == iy0 + 1 always
    const uint64_t hz0 = (uint64_t)iz0 * 83492791ull;
    const uint64_t hz1 = hz0 + 83492791ull;
    idx[0] = base + fastmod(hx0 ^ hy0 ^ hz0, m.T, m.invT);
    idx[1] = base + fastmod(hx0 ^ hy0 ^ hz1, m.T, m.invT);
    idx[2] = base + fastmod(hx0 ^ hy1 ^ hz0, m.T, m.invT);
    idx[3] = base + fastmod(hx0 ^ hy1 ^ hz1, m.T, m.invT);
    idx[4] = base + fastmod(hx1 ^ hy0 ^ hz0, m.T, m.invT);
    idx[5] = base + fastmod(hx1 ^ hy0 ^ hz1, m.T, m.invT);
    idx[6] = base + fastmod(hx1 ^ hy1 ^ hz0, m.T, m.invT);
    idx[7] = base + fastmod(hx1 ^ hy1 ^ hz1, m.T, m.invT);
  }
}

// Block = 256 threads = 4 waves; block owns 64 points.
// Wave w computes levels {w, w+4, w+8, w+12}.
// Points are block-locally counting-sorted by res-4 spatial key so duplicate
// / nearby points sit in adjacent lanes -> the HW coalescer merges their
// line requests. Output goes through an LDS tile -> fully coalesced float4
// NON-TEMPORAL stores (don't evict the table from L2 with output lines).
__global__ __launch_bounds__(NTHR) void hashgrid_fwd(
    const float* __restrict__ xyz,
    const float* __restrict__ wb,
    const float* __restrict__ data,
    float* __restrict__ out,
    Meta meta)
{
#pragma clang fp contract(off)
  const int t    = threadIdx.x;
  const int wave = t >> 6;
  const int lane = t & 63;
  const int pbase = blockIdx.x * BPTS;

  __shared__ float  sxyz[BPTS * 3];      // 768 B
  __shared__ int    hist[64];            // res-4 cell histogram
  __shared__ int    sidx[BPTS];          // sorted -> original point slot
  __shared__ float2 tile[BPTS][NLVL + 1];// +1 pad to spread banks

  if (t < 48) {
    const floatx4 q = __builtin_nontemporal_load(
        reinterpret_cast<const floatx4*>(xyz + pbase * 3) + t);
    reinterpret_cast<floatx4*>(sxyz)[t] = q;
  }
  if (t < 64) hist[t] = 0;
  __syncthreads();

  const float bx0 = wb[0], by0 = wb[1], bz0 = wb[2];
  const float bx1 = wb[3], by1 = wb[4], bz1 = wb[5];
  const float denom = fmaxf(fmaxf(bx1 - bx0, by1 - by0), bz1 - bz0) + 1e-6f;

  // ---- Phase 1: key per original point, histogram (wave 0 only) ----
  int key = 0;
  if (t < 64) {
    float px = fminf(fmaxf(sxyz[t * 3 + 0], bx0), bx1);
    float py = fminf(fmaxf(sxyz[t * 3 + 1], by0), by1);
    float pz = fminf(fmaxf(sxyz[t * 3 + 2], bz0), bz1);
    const float xn = (px - bx0) / denom;
    const float yn = (py - by0) / denom;
    const float zn = (pz - bz0) / denom;
    const int kx = min((int)(xn * 4.0f), 3);
    const int ky = min((int)(yn * 4.0f), 3);
    const int kz = min((int)(zn * 4.0f), 3);
    key = kx * 16 + ky * 4 + kz;
    atomicAdd(&hist[key], 1);
  }
  __syncthreads();

  // ---- Phase 2: inclusive scan of 64 bins (wave 0 shuffle scan) ----
  if (t < 64) {
    int v = hist[t];
#pragma unroll
    for (int d = 1; d < 64; d <<= 1) {
      int u = __shfl_up(v, d, 64);
      if (lane >= d) v += u;
    }
    hist[t] = v;   // inclusive prefix (bin end offset)
  }
  __syncthreads();

  // ---- Phase 3: scatter into sorted order (fill each bin from its end) ----
  if (t < 64) {
    const int pos = atomicSub(&hist[key], 1) - 1;
    sidx[pos] = t;
  }
  __syncthreads();

  // ---- Phase 4: compute; lane processes sorted point ----
  const int p = sidx[lane];
  float px = fminf(fmaxf(sxyz[p * 3 + 0], bx0), bx1);
  float py = fminf(fmaxf(sxyz[p * 3 + 1], by0), by1);
  float pz = fminf(fmaxf(sxyz[p * 3 + 2], bz0), bz1);
  const float xn = (px - bx0) / denom;
  const float yn = (py - by0) / denom;
  const float zn = (pz - bz0) / denom;

  const float2* __restrict__ dp = (const float2*)data;

#pragma unroll 2
  for (int s = 0; s < 4; ++s) {
    const int l = wave + 4 * s;
    int idx[8];
    float o[3];
    level_idx(l, xn, yn, zn, meta, idx, o);
    float2 v[8];
#pragma unroll
    for (int k = 0; k < 8; ++k) v[k] = dp[idx[k]];
    const float wx[2] = {1.0f - o[0], o[0]};
    const float wy[2] = {1.0f - o[1], o[1]};
    const float wz[2] = {1.0f - o[2], o[2]};
    float a0 = 0.0f, a1 = 0.0f;
#pragma unroll
    for (int c = 0; c < 8; ++c) {
      const float w = (wx[(c >> 2) & 1] * wy[(c >> 1) & 1]) * wz[c & 1];
      a0 += w * v[c].x;
      a1 += w * v[c].y;
    }
    tile[p][l] = make_float2(a0, a1);
  }
  __syncthreads();

  // ---- Phase 5: coalesced float4 non-temporal store in original order ----
#pragma unroll
  for (int it = 0; it < 2; ++it) {
    const int idx2 = t + it * NTHR;      // 0..511 float4s
    const int pp = idx2 >> 3;            // point
    const int q  = idx2 & 7;             // float4 within point (levels 2q,2q+1)
    const float2 e0 = tile[pp][2 * q];
    const float2 e1 = tile[pp][2 * q + 1];
    floatx4 r;
    r.x = e0.x; r.y = e0.y; r.z = e1.x; r.w = e1.y;
    __builtin_nontemporal_store(
        r, reinterpret_cast<floatx4*>(out) + (pbase + pp) * 8 + q);
  }
}

static bool isprime_ll(long long v) {
  if (v < 2) return false;
  for (long long i = 2; i * i <= v; ++i)
    if (v % i == 0) return false;
  return true;
}

extern "C" void kernel_launch(void* const* d_in, const int* in_sizes, int n_in,
                              void* d_out, int out_size, void* d_ws, size_t ws_size,
                              hipStream_t stream) {
  (void)in_sizes; (void)n_in; (void)d_ws; (void)ws_size; (void)out_size;

  Meta m;
  long long T = 1LL << 19;
  while (!isprime_ll(T)) ++T;
  const double b = pow(2048.0 / 16.0, 1.0 / 15.0);
  long long off = 0;
  int sh = -1;
  for (int i = 0; i < NLVL; ++i) {
    const int res = (int)(16.0 * pow(b, (double)i));   // matches int(16 * b**i)
    m.scales[i] = res;
    m.offsets[i] = (int)off;
    long long nn = (long long)(res + 1) * (res + 1) * (res + 1);
    if (nn > T) { if (sh < 0) sh = i; nn = T; }
    off += nn;
  }
  m.T = (unsigned int)T;
  m.start_hash = (sh < 0) ? NLVL : sh;
  m.invT = 1.0 / (double)T;

  const float* xyz  = (const float*)d_in[0];
  const float* wbp  = (const float*)d_in[1];
  const float* data = (const float*)d_in[2];
  float* out = (float*)d_out;

  hipLaunchKernelGGL(hashgrid_fwd, dim3(NPTS / BPTS), dim3(NTHR), 0, stream,
                     xyz, wbp, data, out, m);
}